// Round 21
// baseline (249.918 us; speedup 1.0000x reference)
//
#include <hip/hip_runtime.h>
#include <hip/hip_fp16.h>

#define DEG 6
#define RC 10
#define NBATCH 2048
#define FDIM 490
#define KPAD 512
#define HID 4096

typedef _Float16 f16x8 __attribute__((ext_vector_type(8)));
typedef _Float16 f16x4 __attribute__((ext_vector_type(4)));
typedef _Float16 f16x2 __attribute__((ext_vector_type(2)));
typedef float f32x4 __attribute__((ext_vector_type(4)));

// ---------------- prep bodies (device functions; block-uniform callers) ------
__device__ void coef_body(int p, float* __restrict__ Ctab) {
    const int poff[8] = {0, 1, 10, 35, 84, 165, 286, 455};
    const int loff[7] = {0, 1, 28, 153, 496, 1225, 2556};
    int l = 0;
    while (p >= poff[l + 1]) ++l;
    int idx = p - poff[l];
    int nn = 2 * l + 1;
    int mpi = idx / nn, mi = idx % nn;
    int mp = mpi - l, m = mi - l;
    double f[13];
    f[0] = 1.0;
    for (int i = 1; i < 13; ++i) f[i] = f[i - 1] * i;
    double pref = sqrt(f[l + mp] * f[l - mp] * f[l + m] * f[l - m]);
    float* row = Ctab + loff[l] + (size_t)(mpi * nn + mi) * nn;
    for (int q = 0; q < nn; ++q) row[q] = 0.f;
    int s0 = max(0, m - mp), s1 = min(l + m, l - mp);
    for (int s = s0; s <= s1; ++s) {
        int q = mp - m + 2 * s;
        double den = f[l + m - s] * f[s] * f[mp - m + s] * f[l - mp - s];
        double t = pref / den;
        if ((mp - m + s) & 1) t = -t;
        row[q] += (float)t;
    }
}

__device__ void fcw_body(int bx, int by, int tid, const float* __restrict__ W,
                         __half* __restrict__ Wt, _Float16 (*tile)[72]) {
    int k0 = bx * 64;
    int o0 = by * 64;
    int tx = tid & 63, ty = tid >> 6;
    #pragma unroll
    for (int i = 0; i < 16; ++i) {
        int k = k0 + ty + i * 4;
        float v = (k < FDIM) ? W[(size_t)k * HID + o0 + tx] : 0.f;
        tile[ty + i * 4][tx] = (_Float16)v;
    }
    __syncthreads();
    #pragma unroll
    for (int p = 0; p < 2; ++p) {
        int idx = tid + p * 256;
        int ol = idx >> 3;
        int kl = (idx & 7) * 8;
        f16x8 v;
        #pragma unroll
        for (int e = 0; e < 8; ++e) v[e] = tile[kl + e][ol];
        *(f16x8*)(Wt + (size_t)(o0 + ol) * KPAD + k0 + kl) = v;
    }
}

template <int CIN, int COUT>
__device__ void convw_body(int bidx, int tid, const float* __restrict__ K,
                           __half* __restrict__ Bt) {
    int par = bidx >> 2, tap = bidx & 3;
    int pi = par & 1, pj = par >> 1;
    int t1 = tap >> 1, t2 = tap & 1;
    int dh = pi + 2 * t1, dw = pj + 2 * t2;
    const float* Ks = K + (size_t)(dh * 4 + dw) * CIN * COUT;
    int o = tid % COUT;
    int cg = tid / COUT;
    constexpr int NG = 256 / COUT;
    for (int c0 = cg * 8; c0 < CIN; c0 += NG * 8) {
        f16x8 v;
        #pragma unroll
        for (int e = 0; e < 8; ++e) v[e] = (_Float16)Ks[(size_t)(c0 + e) * COUT + o];
        *(f16x8*)(Bt + ((size_t)par * COUT + o) * (4 * CIN) + tap * CIN + c0) = v;
    }
}

__device__ void w4m_body(int t, const float* __restrict__ K4,
                         __half* __restrict__ W4m) {
    int piece = t / 2560;
    int rem = t - piece * 2560;
    int sp = rem / 512;
    int rem2 = rem - sp * 512;
    int row = rem2 >> 5;
    int k = rem2 & 31;
    int h = k >> 4, c = k & 15;
    int s = sp * 2 + h;
    float v = 0.f;
    if (row < 4 && s < 9) {
        int iu = s / 3, iv = s % 3;
        int pi = row & 1, pj = row >> 1;
        int t1 = iu - pi, t2 = iv - pj;
        if (((unsigned)t1 < 2u) && ((unsigned)t2 < 2u)) {
            int dh = pi + 2 * t1, dw = pj + 2 * t2;
            v = K4[(dh * 4 + dw) * 32 + piece * 16 + c];
        }
    }
    W4m[t] = __float2half(v);
}

// ------- ALL weight/coef preps fused into one launch (block-range dispatch) --
__global__ __launch_bounds__(256) void prep_all(
    const float* __restrict__ W, const float* __restrict__ k1,
    const float* __restrict__ k2, const float* __restrict__ k3,
    const float* __restrict__ k4, float* __restrict__ Ctab,
    __half* __restrict__ Wtfc, __half* __restrict__ Bt1,
    __half* __restrict__ Bt2, __half* __restrict__ Bt3,
    __half* __restrict__ W4m) {
    __shared__ _Float16 tile[64][72];
    int blk = blockIdx.x;
    int tid = threadIdx.x;
    if (blk < 2) {
        int p = blk * 256 + tid;
        if (p < 455) coef_body(p, Ctab);
    } else if (blk < 514) {
        int bx = blk - 2;
        fcw_body(bx & 7, bx >> 3, tid, W, Wtfc, tile);
    } else if (blk < 530) {
        convw_body<256, 128>(blk - 514, tid, k1, Bt1);
    } else if (blk < 546) {
        convw_body<128, 64>(blk - 530, tid, k2, Bt2);
    } else if (blk < 562) {
        convw_body<64, 32>(blk - 546, tid, k3, Bt3);
    } else {
        int t = (blk - 562) * 256 + tid;
        if (t < 5120) w4m_body(t, k4, W4m);
    }
}

// ---------------- Wigner D + item projection, FLATTENED across l -------------
// All 455 d/D elements and 490 outputs processed in flat passes: 3 barriers
// (was 28) and full-lane utilization at small l.
__global__ __launch_bounds__(64) void wigner_kernel2(
    const float* __restrict__ angles, const float* __restrict__ item_rep,
    const float* __restrict__ Ctab, __half* __restrict__ item_h) {
    int n = blockIdx.x, lane = threadIdx.x;
    float alpha = angles[n * 3 + 0], beta = angles[n * 3 + 1], gamma = angles[n * 3 + 2];
    float cb = cosf(beta * 0.5f), sb = sinf(beta * 0.5f);
    __shared__ float dsh[455], Dsh[455], Psh[49];
    __shared__ float earA[13], eaiA[13], egrA[13], egiA[13];
    const int eoff[8]  = {0, 1, 10, 35, 84, 165, 286, 455};   // cumulative nn^2
    const int poffp[8] = {0, 1, 4, 9, 16, 25, 36, 49};        // cumulative nn
    const int loff[7]  = {0, 1, 28, 153, 496, 1225, 2556};    // C-table offsets
    const float isq = 0.7071067811865476f;

    if (lane < 13) {
        float mm = (float)(lane - 6);
        float sa, ca; sincosf(alpha * mm, &sa, &ca);
        earA[lane] = ca; eaiA[lane] = -sa;
        float sg, cg; sincosf(gamma * mm, &sg, &cg);
        egrA[lane] = cg; egiA[lane] = -sg;
    }
    if (lane < 49) {
        int l = 0;
        while (lane >= poffp[l + 1]) ++l;
        int q = lane - poffp[l];
        float pv = 1.f;
        for (int i = 0; i < 2 * l - q; ++i) pv *= cb;
        for (int i = 0; i < q; ++i) pv *= sb;
        Psh[lane] = pv;
    }
    __syncthreads();

    // d^l elements, flat over 455
    for (int e = lane; e < 455; e += 64) {
        int l = 0;
        while (e >= eoff[l + 1]) ++l;
        int nn = 2 * l + 1;
        int idx = e - eoff[l];
        const float* cr = Ctab + loff[l] + idx * nn;
        const float* Pl = Psh + poffp[l];
        float acc = 0.f;
        for (int q = 0; q < nn; ++q) acc += cr[q] * Pl[q];
        dsh[e] = acc;
    }
    __syncthreads();

    // real D elements, flat over 455
    for (int e = lane; e < 455; e += 64) {
        int l = 0;
        while (e >= eoff[l + 1]) ++l;
        int nn = 2 * l + 1;
        int idx = e - eoff[l];
        int u = idx / nn, v = idx - u * nn;
        int bn, bi0, bi1; float br0, br1, bm0, bm1;
        int mu = u - l;
        if (mu == 0)      { bn = 1; bi0 = l; br0 = 1.f; bm0 = 0.f; bi1 = 0; br1 = 0.f; bm1 = 0.f; }
        else if (mu > 0)  { bn = 2; bi0 = l + mu; br0 = (mu & 1) ? -isq : isq; bm0 = 0.f;
                            bi1 = l - mu; br1 = isq; bm1 = 0.f; }
        else              { int mm2 = -mu; bn = 2; bi0 = l - mm2; br0 = 0.f; bm0 = isq;
                            bi1 = l + mm2; br1 = 0.f; bm1 = (mm2 & 1) ? isq : -isq; }
        int cn, ci0, ci1; float cr0, cr1, cm0, cm1;
        int nu = v - l;
        if (nu == 0)      { cn = 1; ci0 = l; cr0 = 1.f; cm0 = 0.f; ci1 = 0; cr1 = 0.f; cm1 = 0.f; }
        else if (nu > 0)  { cn = 2; ci0 = l + nu; cr0 = (nu & 1) ? -isq : isq; cm0 = 0.f;
                            ci1 = l - nu; cr1 = isq; cm1 = 0.f; }
        else              { int mm2 = -nu; cn = 2; ci0 = l - mm2; cr0 = 0.f; cm0 = -isq;
                            ci1 = l + mm2; cr1 = 0.f; cm1 = (mm2 & 1) ? -isq : isq; }
        float acc = 0.f;
        #pragma unroll
        for (int pb = 0; pb < 2; ++pb) {
            if (pb >= bn) break;
            int b = pb ? bi1 : bi0;
            float sr = pb ? br1 : br0, si = pb ? bm1 : bm0;
            float er = earA[b - l + 6], ei = eaiA[b - l + 6];
            float z1r = sr * er - si * ei;
            float z1i = sr * ei + si * er;
            #pragma unroll
            for (int pc = 0; pc < 2; ++pc) {
                if (pc >= cn) break;
                int c = pc ? ci1 : ci0;
                float tr = pc ? cr1 : cr0, ti = pc ? cm1 : cm0;
                float dv = dsh[eoff[l] + b * nn + c];
                float gr = egrA[c - l + 6], gi = egiA[c - l + 6];
                float z2r = gr * tr - gi * ti;
                float z2i = gr * ti + gi * tr;
                acc += dv * (z1r * z2r - z1i * z2i);
            }
        }
        Dsh[e] = acc;
    }
    __syncthreads();

    // item projection, flat over 490 outputs
    for (int o = lane; o < FDIM; o += 64) {
        int ua = o / 10, r = o - ua * 10;
        int l = 0;
        while ((l + 1) * (l + 1) <= ua) ++l;
        int nn = 2 * l + 1;
        int u = ua - l * l;
        const float* Dl = Dsh + eoff[l] + u * nn;
        const float* ir = item_rep + (size_t)(l * l) * RC + r;
        float acc = 0.f;
        for (int v = 0; v < nn; ++v) acc += Dl[v] * ir[v * RC];
        item_h[(size_t)n * KPAD + o] = __float2half(acc);
    }
    if (lane < KPAD - FDIM)
        item_h[(size_t)n * KPAD + FDIM + lane] = __float2half(0.f);
}

// ---------------- FC as MFMA GEMM: [2048x512] x [512x4096] + relu -> f16 -----
__global__ __launch_bounds__(256) void fc_mfma(
    const __half* __restrict__ A, const __half* __restrict__ Wt,
    const float* __restrict__ bias, __half* __restrict__ Y) {
    int lane = threadIdx.x & 63, wid = threadIdx.x >> 6;
    int job = blockIdx.x * 4 + wid;
    int mbase = job * 32;
    int cb = blockIdx.y * 128;
    int klane = (lane >> 4) * 8, coll = lane & 15;
    const __half* pA0 = A + (size_t)(mbase + coll) * KPAD + klane;
    const __half* pB0 = Wt + (size_t)(cb + coll) * KPAD + klane;
    f32x4 acc[2][8] = {};
    for (int s = 0; s < 16; ++s) {
        f16x8 a0 = *(const f16x8*)(pA0 + s * 32);
        f16x8 a1 = *(const f16x8*)(pA0 + 16 * KPAD + s * 32);
        #pragma unroll
        for (int f = 0; f < 8; ++f) {
            f16x8 b = *(const f16x8*)(pB0 + (size_t)f * 16 * KPAD + s * 32);
            acc[0][f] = __builtin_amdgcn_mfma_f32_16x16x32_f16(a0, b, acc[0][f], 0, 0, 0);
            acc[1][f] = __builtin_amdgcn_mfma_f32_16x16x32_f16(a1, b, acc[1][f], 0, 0, 0);
        }
    }
    #pragma unroll
    for (int f = 0; f < 8; ++f) {
        float bv = bias[cb + f * 16 + coll];
        #pragma unroll
        for (int r = 0; r < 2; ++r)
            #pragma unroll
            for (int g = 0; g < 4; ++g) {
                int m = mbase + r * 16 + (lane >> 4) * 4 + g;
                float v = acc[r][f][g] + bv;
                v = v > 0.f ? v : 0.f;
                Y[(size_t)m * HID + cb + f * 16 + coll] = __float2half(v);
            }
    }
}

// ------- conv_transpose: A + double-buffered B both in LDS, serial parity ----
template <int CIN, int COUT, int HIN, int R, int LOGH, int CF, int WAVES, int KSPLIT, int OH, int OB, int CHG>
__global__ __launch_bounds__(WAVES * 64) void convt_lds3(
    const __half* __restrict__ X, const __half* __restrict__ Bt,
    const float* __restrict__ bias, __half* __restrict__ Y) {
    constexpr int HH = HIN * HIN;
    constexpr int KTOT = 4 * CIN;
    constexpr int CINS = CIN / KSPLIT;
    constexpr int NSTEPS = CINS / 32;
    constexpr int SL = CIN / 8;
    constexpr int SLB = CINS / 8;
    constexpr int T = WAVES * 64;
    constexpr int PG = WAVES / CHG;
    constexpr int POS = PG * R * 16;
    constexpr int AROWS = POS;
    constexpr int AH = AROWS * CIN;
    constexpr int BROWS = CF * CHG * 16;
    constexpr int BH = BROWS * CINS;
    constexpr int SA = AROWS * SL;
    constexpr int SB = BROWS * SLB;
    constexpr int NSB = SB / T;
    constexpr int NST = 16 * KSPLIT;
    __shared__ _Float16 lds[AH + 2 * BH];

    int tid = threadIdx.x;
    int lane = tid & 63, w = tid >> 6;
    int kg = lane >> 4, coll = lane & 15;
    int pg = w / CHG, cg = w % CHG;
    int n0 = blockIdx.x * (POS >> (2 * LOGH));
    int cbb = blockIdx.y * (CF * CHG * 16);
    int cbase = cbb + cg * (CF * 16);
    int posbase = pg * (R * 16);

    const __half* Xs = X + (size_t)n0 * HH * CIN;
    #pragma unroll
    for (int q = 0; q < SA / T; ++q) {
        int i = tid + q * T;
        int row = i / SL, slot = i % SL;
        f16x8 v = *(const f16x8*)(Xs + (size_t)i * 8);
        *(f16x8*)(&lds[row * CIN + ((slot ^ (row & 7)) * 8)]) = v;
    }
    f16x8 breg[NSB];
    #pragma unroll
    for (int q = 0; q < NSB; ++q) {
        int i = tid + q * T;
        int o = i / SLB, sl = i % SLB;
        breg[q] = *(const f16x8*)(Bt + ((size_t)(cbb + o) * KTOT) + sl * 8);
    }
    #pragma unroll
    for (int q = 0; q < NSB; ++q) {
        int i = tid + q * T;
        int o = i / SLB, sl = i % SLB;
        *(f16x8*)(&lds[AH + o * CINS + ((sl ^ (o & 7)) * 8)]) = breg[q];
    }
    __syncthreads();

    int posl[R]; bool okr[R][3], okc[R][3];
    #pragma unroll
    for (int r = 0; r < R; ++r) {
        int p = posbase + r * 16 + coll;
        posl[r] = p;
        int rem = p & (HH - 1);
        int a = rem >> LOGH, b = rem & (HIN - 1);
        #pragma unroll
        for (int s = 0; s < 3; ++s) {
            okr[r][s] = (unsigned)(a + s - 1) < (unsigned)HIN;
            okc[r][s] = (unsigned)(b + s - 1) < (unsigned)HIN;
        }
    }

    float bvv[CF];
    #pragma unroll
    for (int f = 0; f < CF; ++f) bvv[f] = bias[cbase + f * 16 + coll];

    #pragma unroll
    for (int par = 0; par < 4; ++par) {
        const int pi = par & 1, pj = par >> 1;
        f32x4 acc[R][CF];
        #pragma unroll
        for (int r = 0; r < R; ++r)
            #pragma unroll
            for (int f = 0; f < CF; ++f)
                acc[r][f] = (f32x4){bvv[f], bvv[f], bvv[f], bvv[f]};

        #pragma unroll
        for (int tt = 0; tt < 4 * KSPLIT; ++tt) {
            const int s = par * 4 * KSPLIT + tt;
            const int tap = tt / KSPLIT;
            const int kh = tt % KSPLIT;
            const int buf = s & 1;
            if (s + 1 < NST) {
                const int s2 = s + 1;
                const int par2 = s2 / (4 * KSPLIT);
                const int tt2 = s2 % (4 * KSPLIT);
                const int tap2 = tt2 / KSPLIT;
                const int kh2 = tt2 % KSPLIT;
                #pragma unroll
                for (int q = 0; q < NSB; ++q) {
                    int i = tid + q * T;
                    int o = i / SLB, sl = i % SLB;
                    breg[q] = *(const f16x8*)(Bt +
                        ((size_t)(par2 * COUT + cbb + o) * KTOT +
                         tap2 * CIN + kh2 * CINS) + sl * 8);
                }
            }
            const int iu = (tap >> 1) + pi, iv = (tap & 1) + pj;
            const int delta = (iu - 1) * HIN + (iv - 1);
            int rp[R]; bool ok[R];
            #pragma unroll
            for (int r = 0; r < R; ++r) {
                int t = posl[r] + delta;
                rp[r] = min(max(t, 0), AROWS - 1);
                ok[r] = okr[r][iu] && okc[r][iv];
            }
            const _Float16* Bl = &lds[AH + buf * BH];
            #pragma unroll
            for (int cc = 0; cc < NSTEPS; ++cc) {
                const int slB = cc * 4 + kg;
                const int slA = kh * SLB + slB;
                f16x8 b[CF];
                #pragma unroll
                for (int f = 0; f < CF; ++f) {
                    int ob = cg * (CF * 16) + f * 16 + coll;
                    b[f] = *(const f16x8*)(&Bl[ob * CINS + ((slB ^ (ob & 7)) * 8)]);
                }
                f16x8 a[R];
                #pragma unroll
                for (int r = 0; r < R; ++r) {
                    f16x8 v = *(const f16x8*)(&lds[rp[r] * CIN +
                                                   ((slA ^ (rp[r] & 7)) * 8)]);
                    a[r] = ok[r] ? v : (f16x8){0, 0, 0, 0, 0, 0, 0, 0};
                }
                #pragma unroll
                for (int r = 0; r < R; ++r)
                    #pragma unroll
                    for (int f = 0; f < CF; ++f)
                        acc[r][f] = __builtin_amdgcn_mfma_f32_16x16x32_f16(
                            a[r], b[f], acc[r][f], 0, 0, 0);
            }
            if (s + 1 < NST) {
                #pragma unroll
                for (int q = 0; q < NSB; ++q) {
                    int i = tid + q * T;
                    int o = i / SLB, sl = i % SLB;
                    *(f16x8*)(&lds[AH + ((s + 1) & 1) * BH + o * CINS +
                                   ((sl ^ (o & 7)) * 8)]) = breg[q];
                }
                __syncthreads();
            }
        }

        #pragma unroll
        for (int r = 0; r < R; ++r) {
            #pragma unroll
            for (int g = 0; g < 4; ++g) {
                int p = posbase + r * 16 + kg * 4 + g;
                int ni = p >> (2 * LOGH);
                int rem = p & (HH - 1);
                int a2 = rem >> LOGH, b2 = rem & (HIN - 1);
                size_t ob = (((size_t)(n0 + ni) * OH + 2 * a2 + pi + OB) * OH +
                             2 * b2 + pj + OB) * COUT;
                #pragma unroll
                for (int f = 0; f < CF; ++f) {
                    float v = acc[r][f][g];
                    v = v > 0.f ? v : 0.f;
                    Y[ob + cbase + f * 16 + coll] = __float2half(v);
                }
            }
        }
    }
}

// ------- conv3+conv4 FUSED v7 (round-19, validated) ---------------------------
__global__ __launch_bounds__(512, 4) void conv34_fused7(
    const __half* __restrict__ X, const __half* __restrict__ Bt,
    const float* __restrict__ bias3, const __half* __restrict__ W4m,
    const float* __restrict__ bias4, float* __restrict__ out) {
    constexpr int CIN = 64, HIN = 16, HH = 256, KTOT = 256;
    constexpr int SL = 8, T = 512, AROWS = 256, AH = AROWS * CIN;
    constexpr int BH = 32 * KTOT;
    constexpr int PS = 1164;
    __shared__ _Float16 lds[AH + BH];       // 49,152 B

    int tid = threadIdx.x;
    int lane = tid & 63, w = tid >> 6;
    int kg = lane >> 4, coll = lane & 15;
    int n = blockIdx.x;
    int posbase = w * 32;

    const __half* Xs = X + (size_t)n * HH * CIN;
    #pragma unroll
    for (int q = 0; q < 4; ++q) {
        int i = tid + q * T;
        int row = i / SL, slot = i % SL;
        f16x8 v = *(const f16x8*)(Xs + (size_t)i * 8);
        *(f16x8*)(&lds[row * CIN + ((slot ^ (row & 7)) * 8)]) = v;
    }
    #pragma unroll
    for (int q = 0; q < 2; ++q) {
        int i = tid + q * T;
        int o = i >> 5, sl = i & 31;
        f16x8 b0 = *(const f16x8*)(Bt + (size_t)o * KTOT + sl * 8);
        *(f16x8*)(&lds[AH + o * KTOT + ((sl ^ (o & 7)) * 8)]) = b0;
    }
    __syncthreads();

    int posl[2]; bool okr[2][3], okc[2][3];
    #pragma unroll
    for (int r = 0; r < 2; ++r) {
        int p = posbase + r * 16 + coll;
        posl[r] = p;
        int a = p >> 4, b = p & 15;
        #pragma unroll
        for (int s = 0; s < 3; ++s) {
            okr[r][s] = (unsigned)(a + s - 1) < (unsigned)HIN;
            okc[r][s] = (unsigned)(b + s - 1) < (unsigned)HIN;
        }
    }

    f32x4 ib[2];
    #pragma unroll
    for (int f = 0; f < 2; ++f)
        #pragma unroll
        for (int g = 0; g < 4; ++g) ib[f][g] = bias3[f * 16 + kg * 4 + g];

    f32x4 acc[4][2][2];
    #pragma unroll
    for (int par = 0; par < 4; ++par)
        #pragma unroll
        for (int r = 0; r < 2; ++r) {
            acc[par][r][0] = ib[0];
            acc[par][r][1] = ib[1];
        }

    f16x8 breg[2];
    #pragma unroll
    for (int par = 0; par < 4; ++par) {
        const int pi = par & 1, pj = par >> 1;
        if (par < 3) {
            #pragma unroll
            for (int q = 0; q < 2; ++q) {
                int i = tid + q * T;
                int o = i >> 5, sl = i & 31;
                breg[q] = *(const f16x8*)(Bt + ((size_t)((par + 1) * 32 + o) * KTOT) + sl * 8);
            }
        }
        const _Float16* Bl = &lds[AH];
        #pragma unroll
        for (int tap = 0; tap < 4; ++tap) {
            const int iu = (tap >> 1) + pi, iv = (tap & 1) + pj;
            const int delta = (iu - 1) * HIN + (iv - 1);
            int rp[2]; bool ok[2];
            #pragma unroll
            for (int r = 0; r < 2; ++r) {
                int t2 = posl[r] + delta;
                rp[r] = min(max(t2, 0), AROWS - 1);
                ok[r] = okr[r][iu] && okc[r][iv];
            }
            #pragma unroll
            for (int cc = 0; cc < 2; ++cc) {
                const int slA = cc * 4 + kg;
                const int slB = tap * 8 + slA;
                f16x8 b[2];
                #pragma unroll
                for (int f = 0; f < 2; ++f)
                    b[f] = *(const f16x8*)(&Bl[(f * 16 + coll) * KTOT +
                                               ((slB ^ (coll & 7)) * 8)]);
                f16x8 a[2];
                #pragma unroll
                for (int r = 0; r < 2; ++r) {
                    f16x8 v = *(const f16x8*)(&lds[rp[r] * CIN +
                                                   ((slA ^ (rp[r] & 7)) * 8)]);
                    a[r] = ok[r] ? v : (f16x8){0, 0, 0, 0, 0, 0, 0, 0};
                }
                #pragma unroll
                for (int r = 0; r < 2; ++r)
                    #pragma unroll
                    for (int f = 0; f < 2; ++f)
                        acc[par][r][f] = __builtin_amdgcn_mfma_f32_16x16x32_f16(
                            b[f], a[r], acc[par][r][f], 0, 0, 0);
            }
        }
        if (par < 3) {
            __syncthreads();
            #pragma unroll
            for (int q = 0; q < 2; ++q) {
                int i = tid + q * T;
                int o = i >> 5, sl = i & 31;
                *(f16x8*)(&lds[AH + o * KTOT + ((sl ^ (o & 7)) * 8)]) = breg[q];
            }
            __syncthreads();
        }
    }
    __syncthreads();

    int a_base = w * 4;
    int lane_base = a_base * 34 + coll;
    float bv4 = bias4[0];
    f32x4 acc4[8];
    #pragma unroll
    for (int g2 = 0; g2 < 8; ++g2) acc4[g2] = (f32x4){bv4, bv4, bv4, bv4};

    #pragma unroll
    for (int f = 0; f < 2; ++f) {
        if (f == 0) {
            for (int i = tid; i < 264; i += T) {
                int posi = i >> 1, q = i & 1;
                int rr, sc;
                if (posi < 68) { rr = (posi < 34) ? 0 : 33; sc = posi % 34; }
                else { int e = posi - 68; rr = 1 + (e >> 1); sc = (e & 1) ? 33 : 0; }
                int site = rr * 34 + sc;
                int ss = site ^ ((site >> 2) & 7);
                *(f16x8*)(&lds[(q * PS + ss) * 8]) = (f16x8){0, 0, 0, 0, 0, 0, 0, 0};
            }
        }
        #pragma unroll
        for (int par = 0; par < 4; ++par) {
            const int pi = par & 1, pj = par >> 1;
            #pragma unroll
            for (int r = 0; r < 2; ++r) {
                int p = posl[r];
                int a2 = p >> 4, b2 = p & 15;
                int site = (2 * a2 + pi + 1) * 34 + (2 * b2 + pj + 1);
                int ss = site ^ ((site >> 2) & 7);
                f16x4 pv;
                #pragma unroll
                for (int g = 0; g < 4; ++g) {
                    float v = acc[par][r][f][g];
                    v = v > 0.f ? v : 0.f;
                    pv[g] = (_Float16)v;
                }
                *(f16x4*)(&lds[((kg >> 1) * PS + ss) * 8 + (kg & 1) * 4]) = pv;
            }
        }
        __syncthreads();
        #pragma unroll
        for (int sp = 0; sp < 5; ++sp) {
            f16x8 aw = *(const f16x8*)(W4m + ((size_t)(f * 5 + sp) * 16 + coll) * 32 + kg * 8);
            int s01 = sp * 2 + (kg >> 1);
            int bs = (s01 >= 9) ? 0 : (s01 / 3) * 34 + (s01 % 3);
            int lb = lane_base + bs;
            #pragma unroll
            for (int g2 = 0; g2 < 8; ++g2) {
                int a_loc = g2 >> 1, bh = g2 & 1;
                int site = lb + a_loc * 34 + bh * 16;
                int ss = site ^ ((site >> 2) & 7);
                f16x8 bx = *(const f16x8*)(&lds[((kg & 1) * PS + ss) * 8]);
                acc4[g2] = __builtin_amdgcn_mfma_f32_16x16x32_f16(aw, bx, acc4[g2], 0, 0, 0);
            }
        }
        if (f == 0) __syncthreads();
    }
    if (kg == 0) {
        #pragma unroll
        for (int g2 = 0; g2 < 8; ++g2) {
            int a = a_base + (g2 >> 1);
            int bcol = (g2 & 1) * 32 + 2 * coll;
            float2 v0 = {acc4[g2][0], acc4[g2][2]};
            float2 v1 = {acc4[g2][1], acc4[g2][3]};
            *(float2*)(&out[((size_t)n * 64 + 2 * a) * 64 + bcol]) = v0;
            *(float2*)(&out[((size_t)n * 64 + 2 * a + 1) * 64 + bcol]) = v1;
        }
    }
}

// ---------------- launch -----------------------------------------------------
extern "C" void kernel_launch(void* const* d_in, const int* in_sizes, int n_in,
                              void* d_out, int out_size, void* d_ws, size_t ws_size,
                              hipStream_t stream) {
    const float* angles   = (const float*)d_in[0];
    const float* item_rep = (const float*)d_in[1];
    const float* W        = (const float*)d_in[2];
    const float* bfc      = (const float*)d_in[3];
    const float* k1       = (const float*)d_in[4];
    const float* b1       = (const float*)d_in[5];
    const float* k2       = (const float*)d_in[6];
    const float* b2       = (const float*)d_in[7];
    const float* k3       = (const float*)d_in[8];
    const float* b3       = (const float*)d_in[9];
    const float* k4       = (const float*)d_in[10];
    const float* b4       = (const float*)d_in[11];

    char* ws = (char*)d_ws;
    float*  Ctab  = (float*)(ws + 0);                 //  32 KB
    __half* itemh = (__half*)(ws + 32768);            //   2 MB
    __half* Bt1   = (__half*)(ws + 2129920);          //   1 MB
    __half* Bt2   = (__half*)(ws + 3178496);          // 256 KB
    __half* Bt3   = (__half*)(ws + 3440640);          //  64 KB
    __half* W4m   = (__half*)(ws + 3506176);          //  10 KB
    __half* x0    = (__half*)(ws + 4194304);          //  16 MB -> 20,971,520
    __half* x1    = (__half*)(ws + 20971520);         //  32 MB -> 54,525,952
    __half* Wtfc  = (__half*)(ws + 121634816);        //   4 MB (dead region reuse)
    __half* x2    = (__half*)(ws + 155713536);        //  64 MB -> 222,822,400
    float*  out   = (float*)d_out;

    // ONE fused prep launch: coef + fcw + convw x3 + w4m (582 blocks)
    prep_all<<<582, 256, 0, stream>>>(W, k1, k2, k3, k4,
                                      Ctab, Wtfc, Bt1, Bt2, Bt3, W4m);
    // wigner v2: flattened across l (3 barriers, full lane utilization)
    wigner_kernel2<<<NBATCH, 64, 0, stream>>>(angles, item_rep, Ctab, itemh);
    // FC: 2048x512 @ 512x4096 -> x0
    fc_mfma<<<dim3(16, 32), 256, 0, stream>>>(itemh, Wtfc, bfc, x0);
    // conv1: 4x4x256 -> 8x8x128  (4 waves = 2 pg x 2 cg, R=2, KSPLIT=4)
    convt_lds3<256, 128, 4, 2, 2, 4, 4, 4, 8, 0, 2><<<dim3(512, 1), 256, 0, stream>>>(x0, Bt1, b1, x1);
    // conv2: 8x8x128 -> 16x16x64 (4 waves, R=2, CF=4, CHG=1)
    convt_lds3<128, 64, 8, 2, 3, 4, 4, 1, 16, 0, 1><<<dim3(1024, 1), 256, 0, stream>>>(x1, Bt2, b2, x2);
    // conv3+conv4 fused v7
    conv34_fused7<<<NBATCH, 512, 0, stream>>>(x2, Bt3, b3, W4m, b4, out);
}

// Round 22
// 249.613 us; speedup vs baseline: 1.0012x; 1.0012x over previous
//
#include <hip/hip_runtime.h>
#include <hip/hip_fp16.h>

#define DEG 6
#define RC 10
#define NBATCH 2048
#define FDIM 490
#define KPAD 512
#define HID 4096

typedef _Float16 f16x8 __attribute__((ext_vector_type(8)));
typedef _Float16 f16x4 __attribute__((ext_vector_type(4)));
typedef _Float16 f16x2 __attribute__((ext_vector_type(2)));
typedef float f32x4 __attribute__((ext_vector_type(4)));

// ---------------- prep bodies (device functions; block-uniform callers) ------
__device__ void coef_body(int p, float* __restrict__ Ctab) {
    const int poff[8] = {0, 1, 10, 35, 84, 165, 286, 455};
    const int loff[7] = {0, 1, 28, 153, 496, 1225, 2556};
    int l = 0;
    while (p >= poff[l + 1]) ++l;
    int idx = p - poff[l];
    int nn = 2 * l + 1;
    int mpi = idx / nn, mi = idx % nn;
    int mp = mpi - l, m = mi - l;
    double f[13];
    f[0] = 1.0;
    for (int i = 1; i < 13; ++i) f[i] = f[i - 1] * i;
    double pref = sqrt(f[l + mp] * f[l - mp] * f[l + m] * f[l - m]);
    float* row = Ctab + loff[l] + (size_t)(mpi * nn + mi) * nn;
    for (int q = 0; q < nn; ++q) row[q] = 0.f;
    int s0 = max(0, m - mp), s1 = min(l + m, l - mp);
    for (int s = s0; s <= s1; ++s) {
        int q = mp - m + 2 * s;
        double den = f[l + m - s] * f[s] * f[mp - m + s] * f[l - mp - s];
        double t = pref / den;
        if ((mp - m + s) & 1) t = -t;
        row[q] += (float)t;
    }
}

__device__ void fcw_body(int bx, int by, int tid, const float* __restrict__ W,
                         __half* __restrict__ Wt, _Float16 (*tile)[72]) {
    int k0 = bx * 64;
    int o0 = by * 64;
    int tx = tid & 63, ty = tid >> 6;
    #pragma unroll
    for (int i = 0; i < 16; ++i) {
        int k = k0 + ty + i * 4;
        float v = (k < FDIM) ? W[(size_t)k * HID + o0 + tx] : 0.f;
        tile[ty + i * 4][tx] = (_Float16)v;
    }
    __syncthreads();
    #pragma unroll
    for (int p = 0; p < 2; ++p) {
        int idx = tid + p * 256;
        int ol = idx >> 3;
        int kl = (idx & 7) * 8;
        f16x8 v;
        #pragma unroll
        for (int e = 0; e < 8; ++e) v[e] = tile[kl + e][ol];
        *(f16x8*)(Wt + (size_t)(o0 + ol) * KPAD + k0 + kl) = v;
    }
}

template <int CIN, int COUT>
__device__ void convw_body(int bidx, int tid, const float* __restrict__ K,
                           __half* __restrict__ Bt) {
    int par = bidx >> 2, tap = bidx & 3;
    int pi = par & 1, pj = par >> 1;
    int t1 = tap >> 1, t2 = tap & 1;
    int dh = pi + 2 * t1, dw = pj + 2 * t2;
    const float* Ks = K + (size_t)(dh * 4 + dw) * CIN * COUT;
    int o = tid % COUT;
    int cg = tid / COUT;
    constexpr int NG = 256 / COUT;
    for (int c0 = cg * 8; c0 < CIN; c0 += NG * 8) {
        f16x8 v;
        #pragma unroll
        for (int e = 0; e < 8; ++e) v[e] = (_Float16)Ks[(size_t)(c0 + e) * COUT + o];
        *(f16x8*)(Bt + ((size_t)par * COUT + o) * (4 * CIN) + tap * CIN + c0) = v;
    }
}

__device__ void w4m_body(int t, const float* __restrict__ K4,
                         __half* __restrict__ W4m) {
    int piece = t / 2560;
    int rem = t - piece * 2560;
    int sp = rem / 512;
    int rem2 = rem - sp * 512;
    int row = rem2 >> 5;
    int k = rem2 & 31;
    int h = k >> 4, c = k & 15;
    int s = sp * 2 + h;
    float v = 0.f;
    if (row < 4 && s < 9) {
        int iu = s / 3, iv = s % 3;
        int pi = row & 1, pj = row >> 1;
        int t1 = iu - pi, t2 = iv - pj;
        if (((unsigned)t1 < 2u) && ((unsigned)t2 < 2u)) {
            int dh = pi + 2 * t1, dw = pj + 2 * t2;
            v = K4[(dh * 4 + dw) * 32 + piece * 16 + c];
        }
    }
    W4m[t] = __float2half(v);
}

// ------- ALL weight/coef preps fused into one launch (block-range dispatch) --
__global__ __launch_bounds__(256) void prep_all(
    const float* __restrict__ W, const float* __restrict__ k1,
    const float* __restrict__ k2, const float* __restrict__ k3,
    const float* __restrict__ k4, float* __restrict__ Ctab,
    __half* __restrict__ Wtfc, __half* __restrict__ Bt1,
    __half* __restrict__ Bt2, __half* __restrict__ Bt3,
    __half* __restrict__ W4m) {
    __shared__ _Float16 tile[64][72];
    int blk = blockIdx.x;
    int tid = threadIdx.x;
    if (blk < 2) {
        int p = blk * 256 + tid;
        if (p < 455) coef_body(p, Ctab);
    } else if (blk < 514) {
        int bx = blk - 2;
        fcw_body(bx & 7, bx >> 3, tid, W, Wtfc, tile);
    } else if (blk < 530) {
        convw_body<256, 128>(blk - 514, tid, k1, Bt1);
    } else if (blk < 546) {
        convw_body<128, 64>(blk - 530, tid, k2, Bt2);
    } else if (blk < 562) {
        convw_body<64, 32>(blk - 546, tid, k3, Bt3);
    } else {
        int t = (blk - 562) * 256 + tid;
        if (t < 5120) w4m_body(t, k4, W4m);
    }
}

// ---------------- Wigner D + item projection, FLATTENED across l -------------
// All 455 d/D elements and 490 outputs processed in flat passes: 3 barriers
// (was 28) and full-lane utilization at small l.
__global__ __launch_bounds__(64) void wigner_kernel2(
    const float* __restrict__ angles, const float* __restrict__ item_rep,
    const float* __restrict__ Ctab, __half* __restrict__ item_h) {
    int n = blockIdx.x, lane = threadIdx.x;
    float alpha = angles[n * 3 + 0], beta = angles[n * 3 + 1], gamma = angles[n * 3 + 2];
    float cb = cosf(beta * 0.5f), sb = sinf(beta * 0.5f);
    __shared__ float dsh[455], Dsh[455], Psh[49];
    __shared__ float earA[13], eaiA[13], egrA[13], egiA[13];
    const int eoff[8]  = {0, 1, 10, 35, 84, 165, 286, 455};   // cumulative nn^2
    const int poffp[8] = {0, 1, 4, 9, 16, 25, 36, 49};        // cumulative nn
    const int loff[7]  = {0, 1, 28, 153, 496, 1225, 2556};    // C-table offsets
    const float isq = 0.7071067811865476f;

    if (lane < 13) {
        float mm = (float)(lane - 6);
        float sa, ca; sincosf(alpha * mm, &sa, &ca);
        earA[lane] = ca; eaiA[lane] = -sa;
        float sg, cg; sincosf(gamma * mm, &sg, &cg);
        egrA[lane] = cg; egiA[lane] = -sg;
    }
    if (lane < 49) {
        int l = 0;
        while (lane >= poffp[l + 1]) ++l;
        int q = lane - poffp[l];
        float pv = 1.f;
        for (int i = 0; i < 2 * l - q; ++i) pv *= cb;
        for (int i = 0; i < q; ++i) pv *= sb;
        Psh[lane] = pv;
    }
    __syncthreads();

    // d^l elements, flat over 455
    for (int e = lane; e < 455; e += 64) {
        int l = 0;
        while (e >= eoff[l + 1]) ++l;
        int nn = 2 * l + 1;
        int idx = e - eoff[l];
        const float* cr = Ctab + loff[l] + idx * nn;
        const float* Pl = Psh + poffp[l];
        float acc = 0.f;
        for (int q = 0; q < nn; ++q) acc += cr[q] * Pl[q];
        dsh[e] = acc;
    }
    __syncthreads();

    // real D elements, flat over 455
    for (int e = lane; e < 455; e += 64) {
        int l = 0;
        while (e >= eoff[l + 1]) ++l;
        int nn = 2 * l + 1;
        int idx = e - eoff[l];
        int u = idx / nn, v = idx - u * nn;
        int bn, bi0, bi1; float br0, br1, bm0, bm1;
        int mu = u - l;
        if (mu == 0)      { bn = 1; bi0 = l; br0 = 1.f; bm0 = 0.f; bi1 = 0; br1 = 0.f; bm1 = 0.f; }
        else if (mu > 0)  { bn = 2; bi0 = l + mu; br0 = (mu & 1) ? -isq : isq; bm0 = 0.f;
                            bi1 = l - mu; br1 = isq; bm1 = 0.f; }
        else              { int mm2 = -mu; bn = 2; bi0 = l - mm2; br0 = 0.f; bm0 = isq;
                            bi1 = l + mm2; br1 = 0.f; bm1 = (mm2 & 1) ? isq : -isq; }
        int cn, ci0, ci1; float cr0, cr1, cm0, cm1;
        int nu = v - l;
        if (nu == 0)      { cn = 1; ci0 = l; cr0 = 1.f; cm0 = 0.f; ci1 = 0; cr1 = 0.f; cm1 = 0.f; }
        else if (nu > 0)  { cn = 2; ci0 = l + nu; cr0 = (nu & 1) ? -isq : isq; cm0 = 0.f;
                            ci1 = l - nu; cr1 = isq; cm1 = 0.f; }
        else              { int mm2 = -nu; cn = 2; ci0 = l - mm2; cr0 = 0.f; cm0 = -isq;
                            ci1 = l + mm2; cr1 = 0.f; cm1 = (mm2 & 1) ? -isq : isq; }
        float acc = 0.f;
        #pragma unroll
        for (int pb = 0; pb < 2; ++pb) {
            if (pb >= bn) break;
            int b = pb ? bi1 : bi0;
            float sr = pb ? br1 : br0, si = pb ? bm1 : bm0;
            float er = earA[b - l + 6], ei = eaiA[b - l + 6];
            float z1r = sr * er - si * ei;
            float z1i = sr * ei + si * er;
            #pragma unroll
            for (int pc = 0; pc < 2; ++pc) {
                if (pc >= cn) break;
                int c = pc ? ci1 : ci0;
                float tr = pc ? cr1 : cr0, ti = pc ? cm1 : cm0;
                float dv = dsh[eoff[l] + b * nn + c];
                float gr = egrA[c - l + 6], gi = egiA[c - l + 6];
                float z2r = gr * tr - gi * ti;
                float z2i = gr * ti + gi * tr;
                acc += dv * (z1r * z2r - z1i * z2i);
            }
        }
        Dsh[e] = acc;
    }
    __syncthreads();

    // item projection, flat over 490 outputs
    for (int o = lane; o < FDIM; o += 64) {
        int ua = o / 10, r = o - ua * 10;
        int l = 0;
        while ((l + 1) * (l + 1) <= ua) ++l;
        int nn = 2 * l + 1;
        int u = ua - l * l;
        const float* Dl = Dsh + eoff[l] + u * nn;
        const float* ir = item_rep + (size_t)(l * l) * RC + r;
        float acc = 0.f;
        for (int v = 0; v < nn; ++v) acc += Dl[v] * ir[v * RC];
        item_h[(size_t)n * KPAD + o] = __float2half(acc);
    }
    if (lane < KPAD - FDIM)
        item_h[(size_t)n * KPAD + FDIM + lane] = __float2half(0.f);
}

// ---------------- FC as MFMA GEMM: [2048x512] x [512x4096] + relu -> f16 -----
__global__ __launch_bounds__(256) void fc_mfma(
    const __half* __restrict__ A, const __half* __restrict__ Wt,
    const float* __restrict__ bias, __half* __restrict__ Y) {
    int lane = threadIdx.x & 63, wid = threadIdx.x >> 6;
    int job = blockIdx.x * 4 + wid;
    int mbase = job * 32;
    int cb = blockIdx.y * 128;
    int klane = (lane >> 4) * 8, coll = lane & 15;
    const __half* pA0 = A + (size_t)(mbase + coll) * KPAD + klane;
    const __half* pB0 = Wt + (size_t)(cb + coll) * KPAD + klane;
    f32x4 acc[2][8] = {};
    for (int s = 0; s < 16; ++s) {
        f16x8 a0 = *(const f16x8*)(pA0 + s * 32);
        f16x8 a1 = *(const f16x8*)(pA0 + 16 * KPAD + s * 32);
        #pragma unroll
        for (int f = 0; f < 8; ++f) {
            f16x8 b = *(const f16x8*)(pB0 + (size_t)f * 16 * KPAD + s * 32);
            acc[0][f] = __builtin_amdgcn_mfma_f32_16x16x32_f16(a0, b, acc[0][f], 0, 0, 0);
            acc[1][f] = __builtin_amdgcn_mfma_f32_16x16x32_f16(a1, b, acc[1][f], 0, 0, 0);
        }
    }
    #pragma unroll
    for (int f = 0; f < 8; ++f) {
        float bv = bias[cb + f * 16 + coll];
        #pragma unroll
        for (int r = 0; r < 2; ++r)
            #pragma unroll
            for (int g = 0; g < 4; ++g) {
                int m = mbase + r * 16 + (lane >> 4) * 4 + g;
                float v = acc[r][f][g] + bv;
                v = v > 0.f ? v : 0.f;
                Y[(size_t)m * HID + cb + f * 16 + coll] = __float2half(v);
            }
    }
}

// ------- conv_transpose: A + double-buffered B both in LDS, serial parity ----
template <int CIN, int COUT, int HIN, int R, int LOGH, int CF, int WAVES, int KSPLIT, int OH, int OB, int CHG>
__global__ __launch_bounds__(WAVES * 64) void convt_lds3(
    const __half* __restrict__ X, const __half* __restrict__ Bt,
    const float* __restrict__ bias, __half* __restrict__ Y) {
    constexpr int HH = HIN * HIN;
    constexpr int KTOT = 4 * CIN;
    constexpr int CINS = CIN / KSPLIT;
    constexpr int NSTEPS = CINS / 32;
    constexpr int SL = CIN / 8;
    constexpr int SLB = CINS / 8;
    constexpr int T = WAVES * 64;
    constexpr int PG = WAVES / CHG;
    constexpr int POS = PG * R * 16;
    constexpr int AROWS = POS;
    constexpr int AH = AROWS * CIN;
    constexpr int BROWS = CF * CHG * 16;
    constexpr int BH = BROWS * CINS;
    constexpr int SA = AROWS * SL;
    constexpr int SB = BROWS * SLB;
    constexpr int NSB = SB / T;
    constexpr int NST = 16 * KSPLIT;
    __shared__ _Float16 lds[AH + 2 * BH];

    int tid = threadIdx.x;
    int lane = tid & 63, w = tid >> 6;
    int kg = lane >> 4, coll = lane & 15;
    int pg = w / CHG, cg = w % CHG;
    int n0 = blockIdx.x * (POS >> (2 * LOGH));
    int cbb = blockIdx.y * (CF * CHG * 16);
    int cbase = cbb + cg * (CF * 16);
    int posbase = pg * (R * 16);

    const __half* Xs = X + (size_t)n0 * HH * CIN;
    #pragma unroll
    for (int q = 0; q < SA / T; ++q) {
        int i = tid + q * T;
        int row = i / SL, slot = i % SL;
        f16x8 v = *(const f16x8*)(Xs + (size_t)i * 8);
        *(f16x8*)(&lds[row * CIN + ((slot ^ (row & 7)) * 8)]) = v;
    }
    f16x8 breg[NSB];
    #pragma unroll
    for (int q = 0; q < NSB; ++q) {
        int i = tid + q * T;
        int o = i / SLB, sl = i % SLB;
        breg[q] = *(const f16x8*)(Bt + ((size_t)(cbb + o) * KTOT) + sl * 8);
    }
    #pragma unroll
    for (int q = 0; q < NSB; ++q) {
        int i = tid + q * T;
        int o = i / SLB, sl = i % SLB;
        *(f16x8*)(&lds[AH + o * CINS + ((sl ^ (o & 7)) * 8)]) = breg[q];
    }
    __syncthreads();

    int posl[R]; bool okr[R][3], okc[R][3];
    #pragma unroll
    for (int r = 0; r < R; ++r) {
        int p = posbase + r * 16 + coll;
        posl[r] = p;
        int rem = p & (HH - 1);
        int a = rem >> LOGH, b = rem & (HIN - 1);
        #pragma unroll
        for (int s = 0; s < 3; ++s) {
            okr[r][s] = (unsigned)(a + s - 1) < (unsigned)HIN;
            okc[r][s] = (unsigned)(b + s - 1) < (unsigned)HIN;
        }
    }

    float bvv[CF];
    #pragma unroll
    for (int f = 0; f < CF; ++f) bvv[f] = bias[cbase + f * 16 + coll];

    #pragma unroll
    for (int par = 0; par < 4; ++par) {
        const int pi = par & 1, pj = par >> 1;
        f32x4 acc[R][CF];
        #pragma unroll
        for (int r = 0; r < R; ++r)
            #pragma unroll
            for (int f = 0; f < CF; ++f)
                acc[r][f] = (f32x4){bvv[f], bvv[f], bvv[f], bvv[f]};

        #pragma unroll
        for (int tt = 0; tt < 4 * KSPLIT; ++tt) {
            const int s = par * 4 * KSPLIT + tt;
            const int tap = tt / KSPLIT;
            const int kh = tt % KSPLIT;
            const int buf = s & 1;
            if (s + 1 < NST) {
                const int s2 = s + 1;
                const int par2 = s2 / (4 * KSPLIT);
                const int tt2 = s2 % (4 * KSPLIT);
                const int tap2 = tt2 / KSPLIT;
                const int kh2 = tt2 % KSPLIT;
                #pragma unroll
                for (int q = 0; q < NSB; ++q) {
                    int i = tid + q * T;
                    int o = i / SLB, sl = i % SLB;
                    breg[q] = *(const f16x8*)(Bt +
                        ((size_t)(par2 * COUT + cbb + o) * KTOT +
                         tap2 * CIN + kh2 * CINS) + sl * 8);
                }
            }
            const int iu = (tap >> 1) + pi, iv = (tap & 1) + pj;
            const int delta = (iu - 1) * HIN + (iv - 1);
            int rp[R]; bool ok[R];
            #pragma unroll
            for (int r = 0; r < R; ++r) {
                int t = posl[r] + delta;
                rp[r] = min(max(t, 0), AROWS - 1);
                ok[r] = okr[r][iu] && okc[r][iv];
            }
            const _Float16* Bl = &lds[AH + buf * BH];
            #pragma unroll
            for (int cc = 0; cc < NSTEPS; ++cc) {
                const int slB = cc * 4 + kg;
                const int slA = kh * SLB + slB;
                f16x8 b[CF];
                #pragma unroll
                for (int f = 0; f < CF; ++f) {
                    int ob = cg * (CF * 16) + f * 16 + coll;
                    b[f] = *(const f16x8*)(&Bl[ob * CINS + ((slB ^ (ob & 7)) * 8)]);
                }
                f16x8 a[R];
                #pragma unroll
                for (int r = 0; r < R; ++r) {
                    f16x8 v = *(const f16x8*)(&lds[rp[r] * CIN +
                                                   ((slA ^ (rp[r] & 7)) * 8)]);
                    a[r] = ok[r] ? v : (f16x8){0, 0, 0, 0, 0, 0, 0, 0};
                }
                #pragma unroll
                for (int r = 0; r < R; ++r)
                    #pragma unroll
                    for (int f = 0; f < CF; ++f)
                        acc[r][f] = __builtin_amdgcn_mfma_f32_16x16x32_f16(
                            a[r], b[f], acc[r][f], 0, 0, 0);
            }
            if (s + 1 < NST) {
                #pragma unroll
                for (int q = 0; q < NSB; ++q) {
                    int i = tid + q * T;
                    int o = i / SLB, sl = i % SLB;
                    *(f16x8*)(&lds[AH + ((s + 1) & 1) * BH + o * CINS +
                                   ((sl ^ (o & 7)) * 8)]) = breg[q];
                }
                __syncthreads();
            }
        }

        #pragma unroll
        for (int r = 0; r < R; ++r) {
            #pragma unroll
            for (int g = 0; g < 4; ++g) {
                int p = posbase + r * 16 + kg * 4 + g;
                int ni = p >> (2 * LOGH);
                int rem = p & (HH - 1);
                int a2 = rem >> LOGH, b2 = rem & (HIN - 1);
                size_t ob = (((size_t)(n0 + ni) * OH + 2 * a2 + pi + OB) * OH +
                             2 * b2 + pj + OB) * COUT;
                #pragma unroll
                for (int f = 0; f < CF; ++f) {
                    float v = acc[r][f][g];
                    v = v > 0.f ? v : 0.f;
                    Y[ob + cbase + f * 16 + coll] = __float2half(v);
                }
            }
        }
    }
}

// ------- conv3+conv4 FUSED v7 (round-19, validated) ---------------------------
__global__ __launch_bounds__(512, 4) void conv34_fused7(
    const __half* __restrict__ X, const __half* __restrict__ Bt,
    const float* __restrict__ bias3, const __half* __restrict__ W4m,
    const float* __restrict__ bias4, float* __restrict__ out) {
    constexpr int CIN = 64, HIN = 16, HH = 256, KTOT = 256;
    constexpr int SL = 8, T = 512, AROWS = 256, AH = AROWS * CIN;
    constexpr int BH = 32 * KTOT;
    constexpr int PS = 1164;
    __shared__ _Float16 lds[AH + BH];       // 49,152 B

    int tid = threadIdx.x;
    int lane = tid & 63, w = tid >> 6;
    int kg = lane >> 4, coll = lane & 15;
    int n = blockIdx.x;
    int posbase = w * 32;

    const __half* Xs = X + (size_t)n * HH * CIN;
    #pragma unroll
    for (int q = 0; q < 4; ++q) {
        int i = tid + q * T;
        int row = i / SL, slot = i % SL;
        f16x8 v = *(const f16x8*)(Xs + (size_t)i * 8);
        *(f16x8*)(&lds[row * CIN + ((slot ^ (row & 7)) * 8)]) = v;
    }
    #pragma unroll
    for (int q = 0; q < 2; ++q) {
        int i = tid + q * T;
        int o = i >> 5, sl = i & 31;
        f16x8 b0 = *(const f16x8*)(Bt + (size_t)o * KTOT + sl * 8);
        *(f16x8*)(&lds[AH + o * KTOT + ((sl ^ (o & 7)) * 8)]) = b0;
    }
    __syncthreads();

    int posl[2]; bool okr[2][3], okc[2][3];
    #pragma unroll
    for (int r = 0; r < 2; ++r) {
        int p = posbase + r * 16 + coll;
        posl[r] = p;
        int a = p >> 4, b = p & 15;
        #pragma unroll
        for (int s = 0; s < 3; ++s) {
            okr[r][s] = (unsigned)(a + s - 1) < (unsigned)HIN;
            okc[r][s] = (unsigned)(b + s - 1) < (unsigned)HIN;
        }
    }

    f32x4 ib[2];
    #pragma unroll
    for (int f = 0; f < 2; ++f)
        #pragma unroll
        for (int g = 0; g < 4; ++g) ib[f][g] = bias3[f * 16 + kg * 4 + g];

    f32x4 acc[4][2][2];
    #pragma unroll
    for (int par = 0; par < 4; ++par)
        #pragma unroll
        for (int r = 0; r < 2; ++r) {
            acc[par][r][0] = ib[0];
            acc[par][r][1] = ib[1];
        }

    f16x8 breg[2];
    #pragma unroll
    for (int par = 0; par < 4; ++par) {
        const int pi = par & 1, pj = par >> 1;
        if (par < 3) {
            #pragma unroll
            for (int q = 0; q < 2; ++q) {
                int i = tid + q * T;
                int o = i >> 5, sl = i & 31;
                breg[q] = *(const f16x8*)(Bt + ((size_t)((par + 1) * 32 + o) * KTOT) + sl * 8);
            }
        }
        const _Float16* Bl = &lds[AH];
        #pragma unroll
        for (int tap = 0; tap < 4; ++tap) {
            const int iu = (tap >> 1) + pi, iv = (tap & 1) + pj;
            const int delta = (iu - 1) * HIN + (iv - 1);
            int rp[2]; bool ok[2];
            #pragma unroll
            for (int r = 0; r < 2; ++r) {
                int t2 = posl[r] + delta;
                rp[r] = min(max(t2, 0), AROWS - 1);
                ok[r] = okr[r][iu] && okc[r][iv];
            }
            #pragma unroll
            for (int cc = 0; cc < 2; ++cc) {
                const int slA = cc * 4 + kg;
                const int slB = tap * 8 + slA;
                f16x8 b[2];
                #pragma unroll
                for (int f = 0; f < 2; ++f)
                    b[f] = *(const f16x8*)(&Bl[(f * 16 + coll) * KTOT +
                                               ((slB ^ (coll & 7)) * 8)]);
                f16x8 a[2];
                #pragma unroll
                for (int r = 0; r < 2; ++r) {
                    f16x8 v = *(const f16x8*)(&lds[rp[r] * CIN +
                                                   ((slA ^ (rp[r] & 7)) * 8)]);
                    a[r] = ok[r] ? v : (f16x8){0, 0, 0, 0, 0, 0, 0, 0};
                }
                #pragma unroll
                for (int r = 0; r < 2; ++r)
                    #pragma unroll
                    for (int f = 0; f < 2; ++f)
                        acc[par][r][f] = __builtin_amdgcn_mfma_f32_16x16x32_f16(
                            b[f], a[r], acc[par][r][f], 0, 0, 0);
            }
        }
        if (par < 3) {
            __syncthreads();
            #pragma unroll
            for (int q = 0; q < 2; ++q) {
                int i = tid + q * T;
                int o = i >> 5, sl = i & 31;
                *(f16x8*)(&lds[AH + o * KTOT + ((sl ^ (o & 7)) * 8)]) = breg[q];
            }
            __syncthreads();
        }
    }
    __syncthreads();

    int a_base = w * 4;
    int lane_base = a_base * 34 + coll;
    float bv4 = bias4[0];
    f32x4 acc4[8];
    #pragma unroll
    for (int g2 = 0; g2 < 8; ++g2) acc4[g2] = (f32x4){bv4, bv4, bv4, bv4};

    #pragma unroll
    for (int f = 0; f < 2; ++f) {
        if (f == 0) {
            for (int i = tid; i < 264; i += T) {
                int posi = i >> 1, q = i & 1;
                int rr, sc;
                if (posi < 68) { rr = (posi < 34) ? 0 : 33; sc = posi % 34; }
                else { int e = posi - 68; rr = 1 + (e >> 1); sc = (e & 1) ? 33 : 0; }
                int site = rr * 34 + sc;
                int ss = site ^ ((site >> 2) & 7);
                *(f16x8*)(&lds[(q * PS + ss) * 8]) = (f16x8){0, 0, 0, 0, 0, 0, 0, 0};
            }
        }
        #pragma unroll
        for (int par = 0; par < 4; ++par) {
            const int pi = par & 1, pj = par >> 1;
            #pragma unroll
            for (int r = 0; r < 2; ++r) {
                int p = posl[r];
                int a2 = p >> 4, b2 = p & 15;
                int site = (2 * a2 + pi + 1) * 34 + (2 * b2 + pj + 1);
                int ss = site ^ ((site >> 2) & 7);
                f16x4 pv;
                #pragma unroll
                for (int g = 0; g < 4; ++g) {
                    float v = acc[par][r][f][g];
                    v = v > 0.f ? v : 0.f;
                    pv[g] = (_Float16)v;
                }
                *(f16x4*)(&lds[((kg >> 1) * PS + ss) * 8 + (kg & 1) * 4]) = pv;
            }
        }
        __syncthreads();
        #pragma unroll
        for (int sp = 0; sp < 5; ++sp) {
            f16x8 aw = *(const f16x8*)(W4m + ((size_t)(f * 5 + sp) * 16 + coll) * 32 + kg * 8);
            int s01 = sp * 2 + (kg >> 1);
            int bs = (s01 >= 9) ? 0 : (s01 / 3) * 34 + (s01 % 3);
            int lb = lane_base + bs;
            #pragma unroll
            for (int g2 = 0; g2 < 8; ++g2) {
                int a_loc = g2 >> 1, bh = g2 & 1;
                int site = lb + a_loc * 34 + bh * 16;
                int ss = site ^ ((site >> 2) & 7);
                f16x8 bx = *(const f16x8*)(&lds[((kg & 1) * PS + ss) * 8]);
                acc4[g2] = __builtin_amdgcn_mfma_f32_16x16x32_f16(aw, bx, acc4[g2], 0, 0, 0);
            }
        }
        if (f == 0) __syncthreads();
    }
    if (kg == 0) {
        #pragma unroll
        for (int g2 = 0; g2 < 8; ++g2) {
            int a = a_base + (g2 >> 1);
            int bcol = (g2 & 1) * 32 + 2 * coll;
            float2 v0 = {acc4[g2][0], acc4[g2][2]};
            float2 v1 = {acc4[g2][1], acc4[g2][3]};
            *(float2*)(&out[((size_t)n * 64 + 2 * a) * 64 + bcol]) = v0;
            *(float2*)(&out[((size_t)n * 64 + 2 * a + 1) * 64 + bcol]) = v1;
        }
    }
}

// ---------------- launch -----------------------------------------------------
extern "C" void kernel_launch(void* const* d_in, const int* in_sizes, int n_in,
                              void* d_out, int out_size, void* d_ws, size_t ws_size,
                              hipStream_t stream) {
    const float* angles   = (const float*)d_in[0];
    const float* item_rep = (const float*)d_in[1];
    const float* W        = (const float*)d_in[2];
    const float* bfc      = (const float*)d_in[3];
    const float* k1       = (const float*)d_in[4];
    const float* b1       = (const float*)d_in[5];
    const float* k2       = (const float*)d_in[6];
    const float* b2       = (const float*)d_in[7];
    const float* k3       = (const float*)d_in[8];
    const float* b3       = (const float*)d_in[9];
    const float* k4       = (const float*)d_in[10];
    const float* b4       = (const float*)d_in[11];

    char* ws = (char*)d_ws;
    float*  Ctab  = (float*)(ws + 0);                 //  32 KB
    __half* itemh = (__half*)(ws + 32768);            //   2 MB
    __half* Bt1   = (__half*)(ws + 2129920);          //   1 MB
    __half* Bt2   = (__half*)(ws + 3178496);          // 256 KB
    __half* Bt3   = (__half*)(ws + 3440640);          //  64 KB
    __half* W4m   = (__half*)(ws + 3506176);          //  10 KB
    __half* x0    = (__half*)(ws + 4194304);          //  16 MB -> 20,971,520
    __half* x1    = (__half*)(ws + 20971520);         //  32 MB -> 54,525,952
    __half* Wtfc  = (__half*)(ws + 121634816);        //   4 MB (dead region reuse)
    __half* x2    = (__half*)(ws + 155713536);        //  64 MB -> 222,822,400
    float*  out   = (float*)d_out;

    // ONE fused prep launch: coef + fcw + convw x3 + w4m (582 blocks)
    prep_all<<<582, 256, 0, stream>>>(W, k1, k2, k3, k4,
                                      Ctab, Wtfc, Bt1, Bt2, Bt3, W4m);
    // wigner v2: flattened across l (3 barriers, full lane utilization)
    wigner_kernel2<<<NBATCH, 64, 0, stream>>>(angles, item_rep, Ctab, itemh);
    // FC: 2048x512 @ 512x4096 -> x0
    fc_mfma<<<dim3(16, 32), 256, 0, stream>>>(itemh, Wtfc, bfc, x0);
    // conv1: 4x4x256 -> 8x8x128  (4 waves = 2 pg x 2 cg, R=2, KSPLIT=4)
    convt_lds3<256, 128, 4, 2, 2, 4, 4, 4, 8, 0, 2><<<dim3(512, 1), 256, 0, stream>>>(x0, Bt1, b1, x1);
    // conv2: 8x8x128 -> 16x16x64 (4 waves, R=2, CF=4, CHG=1)
    convt_lds3<128, 64, 8, 2, 3, 4, 4, 1, 16, 0, 1><<<dim3(1024, 1), 256, 0, stream>>>(x1, Bt2, b2, x2);
    // conv3+conv4 fused v7
    conv34_fused7<<<NBATCH, 512, 0, stream>>>(x2, Bt3, b3, W4m, b4, out);
}

// Round 23
// 234.609 us; speedup vs baseline: 1.0653x; 1.0640x over previous
//
#include <hip/hip_runtime.h>
#include <hip/hip_fp16.h>

#define DEG 6
#define RC 10
#define NBATCH 2048
#define FDIM 490
#define KPAD 512
#define HID 4096

typedef _Float16 f16x8 __attribute__((ext_vector_type(8)));
typedef _Float16 f16x4 __attribute__((ext_vector_type(4)));
typedef _Float16 f16x2 __attribute__((ext_vector_type(2)));
typedef float f32x4 __attribute__((ext_vector_type(4)));

// ---------------- prep bodies (device functions; block-uniform callers) ------
__device__ void coef_body(int p, float* __restrict__ Ctab) {
    const int poff[8] = {0, 1, 10, 35, 84, 165, 286, 455};
    const int loff[7] = {0, 1, 28, 153, 496, 1225, 2556};
    int l = 0;
    while (p >= poff[l + 1]) ++l;
    int idx = p - poff[l];
    int nn = 2 * l + 1;
    int mpi = idx / nn, mi = idx % nn;
    int mp = mpi - l, m = mi - l;
    double f[13];
    f[0] = 1.0;
    for (int i = 1; i < 13; ++i) f[i] = f[i - 1] * i;
    double pref = sqrt(f[l + mp] * f[l - mp] * f[l + m] * f[l - m]);
    float* row = Ctab + loff[l] + (size_t)(mpi * nn + mi) * nn;
    for (int q = 0; q < nn; ++q) row[q] = 0.f;
    int s0 = max(0, m - mp), s1 = min(l + m, l - mp);
    for (int s = s0; s <= s1; ++s) {
        int q = mp - m + 2 * s;
        double den = f[l + m - s] * f[s] * f[mp - m + s] * f[l - mp - s];
        double t = pref / den;
        if ((mp - m + s) & 1) t = -t;
        row[q] += (float)t;
    }
}

// fcw: W[490,4096] f32 -> Wt2 k-chunked [s(16)][o(4096)][32 halves] f16
__device__ void fcw_body(int bx, int by, int tid, const float* __restrict__ W,
                         __half* __restrict__ Wt2, _Float16 (*tile)[72]) {
    int k0 = bx * 64;
    int o0 = by * 64;
    int tx = tid & 63, ty = tid >> 6;
    #pragma unroll
    for (int i = 0; i < 16; ++i) {
        int k = k0 + ty + i * 4;
        float v = (k < FDIM) ? W[(size_t)k * HID + o0 + tx] : 0.f;
        tile[ty + i * 4][tx] = (_Float16)v;
    }
    __syncthreads();
    #pragma unroll
    for (int p = 0; p < 2; ++p) {
        int idx = tid + p * 256;
        int ol = idx >> 3;
        int kl = (idx & 7) * 8;
        f16x8 v;
        #pragma unroll
        for (int e = 0; e < 8; ++e) v[e] = tile[kl + e][ol];
        int k = k0 + kl;
        *(f16x8*)(Wt2 + ((size_t)(k >> 5) * HID + o0 + ol) * 32 + (k & 31)) = v;
    }
}

template <int CIN, int COUT>
__device__ void convw_body(int bidx, int tid, const float* __restrict__ K,
                           __half* __restrict__ Bt) {
    int par = bidx >> 2, tap = bidx & 3;
    int pi = par & 1, pj = par >> 1;
    int t1 = tap >> 1, t2 = tap & 1;
    int dh = pi + 2 * t1, dw = pj + 2 * t2;
    const float* Ks = K + (size_t)(dh * 4 + dw) * CIN * COUT;
    int o = tid % COUT;
    int cg = tid / COUT;
    constexpr int NG = 256 / COUT;
    for (int c0 = cg * 8; c0 < CIN; c0 += NG * 8) {
        f16x8 v;
        #pragma unroll
        for (int e = 0; e < 8; ++e) v[e] = (_Float16)Ks[(size_t)(c0 + e) * COUT + o];
        *(f16x8*)(Bt + ((size_t)par * COUT + o) * (4 * CIN) + tap * CIN + c0) = v;
    }
}

__device__ void w4m_body(int t, const float* __restrict__ K4,
                         __half* __restrict__ W4m) {
    int piece = t / 2560;
    int rem = t - piece * 2560;
    int sp = rem / 512;
    int rem2 = rem - sp * 512;
    int row = rem2 >> 5;
    int k = rem2 & 31;
    int h = k >> 4, c = k & 15;
    int s = sp * 2 + h;
    float v = 0.f;
    if (row < 4 && s < 9) {
        int iu = s / 3, iv = s % 3;
        int pi = row & 1, pj = row >> 1;
        int t1 = iu - pi, t2 = iv - pj;
        if (((unsigned)t1 < 2u) && ((unsigned)t2 < 2u)) {
            int dh = pi + 2 * t1, dw = pj + 2 * t2;
            v = K4[(dh * 4 + dw) * 32 + piece * 16 + c];
        }
    }
    W4m[t] = __float2half(v);
}

// ------- ALL weight/coef preps fused into one launch (block-range dispatch) --
__global__ __launch_bounds__(256) void prep_all(
    const float* __restrict__ W, const float* __restrict__ k1,
    const float* __restrict__ k2, const float* __restrict__ k3,
    const float* __restrict__ k4, float* __restrict__ Ctab,
    __half* __restrict__ Wtfc, __half* __restrict__ Bt1,
    __half* __restrict__ Bt2, __half* __restrict__ Bt3,
    __half* __restrict__ W4m) {
    __shared__ _Float16 tile[64][72];
    int blk = blockIdx.x;
    int tid = threadIdx.x;
    if (blk < 2) {
        int p = blk * 256 + tid;
        if (p < 455) coef_body(p, Ctab);
    } else if (blk < 514) {
        int bx = blk - 2;
        fcw_body(bx & 7, bx >> 3, tid, W, Wtfc, tile);
    } else if (blk < 530) {
        convw_body<256, 128>(blk - 514, tid, k1, Bt1);
    } else if (blk < 546) {
        convw_body<128, 64>(blk - 530, tid, k2, Bt2);
    } else if (blk < 562) {
        convw_body<64, 32>(blk - 546, tid, k3, Bt3);
    } else {
        int t = (blk - 562) * 256 + tid;
        if (t < 5120) w4m_body(t, k4, W4m);
    }
}

// ---------------- Wigner D + item projection, FLATTENED across l -------------
// Output: item2 k-chunked [s(16)][n(2048)][32 halves] f16 (for coalesced fc).
__global__ __launch_bounds__(64) void wigner_kernel2(
    const float* __restrict__ angles, const float* __restrict__ item_rep,
    const float* __restrict__ Ctab, __half* __restrict__ item2) {
    int n = blockIdx.x, lane = threadIdx.x;
    float alpha = angles[n * 3 + 0], beta = angles[n * 3 + 1], gamma = angles[n * 3 + 2];
    float cb = cosf(beta * 0.5f), sb = sinf(beta * 0.5f);
    __shared__ float dsh[455], Dsh[455], Psh[49];
    __shared__ float earA[13], eaiA[13], egrA[13], egiA[13];
    const int eoff[8]  = {0, 1, 10, 35, 84, 165, 286, 455};
    const int poffp[8] = {0, 1, 4, 9, 16, 25, 36, 49};
    const int loff[7]  = {0, 1, 28, 153, 496, 1225, 2556};
    const float isq = 0.7071067811865476f;

    if (lane < 13) {
        float mm = (float)(lane - 6);
        float sa, ca; sincosf(alpha * mm, &sa, &ca);
        earA[lane] = ca; eaiA[lane] = -sa;
        float sg, cg; sincosf(gamma * mm, &sg, &cg);
        egrA[lane] = cg; egiA[lane] = -sg;
    }
    if (lane < 49) {
        int l = 0;
        while (lane >= poffp[l + 1]) ++l;
        int q = lane - poffp[l];
        float pv = 1.f;
        for (int i = 0; i < 2 * l - q; ++i) pv *= cb;
        for (int i = 0; i < q; ++i) pv *= sb;
        Psh[lane] = pv;
    }
    __syncthreads();

    for (int e = lane; e < 455; e += 64) {
        int l = 0;
        while (e >= eoff[l + 1]) ++l;
        int nn = 2 * l + 1;
        int idx = e - eoff[l];
        const float* cr = Ctab + loff[l] + idx * nn;
        const float* Pl = Psh + poffp[l];
        float acc = 0.f;
        for (int q = 0; q < nn; ++q) acc += cr[q] * Pl[q];
        dsh[e] = acc;
    }
    __syncthreads();

    for (int e = lane; e < 455; e += 64) {
        int l = 0;
        while (e >= eoff[l + 1]) ++l;
        int nn = 2 * l + 1;
        int idx = e - eoff[l];
        int u = idx / nn, v = idx - u * nn;
        int bn, bi0, bi1; float br0, br1, bm0, bm1;
        int mu = u - l;
        if (mu == 0)      { bn = 1; bi0 = l; br0 = 1.f; bm0 = 0.f; bi1 = 0; br1 = 0.f; bm1 = 0.f; }
        else if (mu > 0)  { bn = 2; bi0 = l + mu; br0 = (mu & 1) ? -isq : isq; bm0 = 0.f;
                            bi1 = l - mu; br1 = isq; bm1 = 0.f; }
        else              { int mm2 = -mu; bn = 2; bi0 = l - mm2; br0 = 0.f; bm0 = isq;
                            bi1 = l + mm2; br1 = 0.f; bm1 = (mm2 & 1) ? isq : -isq; }
        int cn, ci0, ci1; float cr0, cr1, cm0, cm1;
        int nu = v - l;
        if (nu == 0)      { cn = 1; ci0 = l; cr0 = 1.f; cm0 = 0.f; ci1 = 0; cr1 = 0.f; cm1 = 0.f; }
        else if (nu > 0)  { cn = 2; ci0 = l + nu; cr0 = (nu & 1) ? -isq : isq; cm0 = 0.f;
                            ci1 = l - nu; cr1 = isq; cm1 = 0.f; }
        else              { int mm2 = -nu; cn = 2; ci0 = l - mm2; cr0 = 0.f; cm0 = -isq;
                            ci1 = l + mm2; cr1 = 0.f; cm1 = (mm2 & 1) ? -isq : isq; }
        float acc = 0.f;
        #pragma unroll
        for (int pb = 0; pb < 2; ++pb) {
            if (pb >= bn) break;
            int b = pb ? bi1 : bi0;
            float sr = pb ? br1 : br0, si = pb ? bm1 : bm0;
            float er = earA[b - l + 6], ei = eaiA[b - l + 6];
            float z1r = sr * er - si * ei;
            float z1i = sr * ei + si * er;
            #pragma unroll
            for (int pc = 0; pc < 2; ++pc) {
                if (pc >= cn) break;
                int c = pc ? ci1 : ci0;
                float tr = pc ? cr1 : cr0, ti = pc ? cm1 : cm0;
                float dv = dsh[eoff[l] + b * nn + c];
                float gr = egrA[c - l + 6], gi = egiA[c - l + 6];
                float z2r = gr * tr - gi * ti;
                float z2i = gr * ti + gi * tr;
                acc += dv * (z1r * z2r - z1i * z2i);
            }
        }
        Dsh[e] = acc;
    }
    __syncthreads();

    for (int o = lane; o < FDIM; o += 64) {
        int ua = o / 10, r = o - ua * 10;
        int l = 0;
        while ((l + 1) * (l + 1) <= ua) ++l;
        int nn = 2 * l + 1;
        int u = ua - l * l;
        const float* Dl = Dsh + eoff[l] + u * nn;
        const float* ir = item_rep + (size_t)(l * l) * RC + r;
        float acc = 0.f;
        for (int v = 0; v < nn; ++v) acc += Dl[v] * ir[v * RC];
        item2[((size_t)(o >> 5) * NBATCH + n) * 32 + (o & 31)] = __float2half(acc);
    }
    if (lane < KPAD - FDIM) {
        int o = FDIM + lane;
        item2[((size_t)(o >> 5) * NBATCH + n) * 32 + (o & 31)] = __float2half(0.f);
    }
}

// ------ FC as MFMA GEMM, COALESCED loads via k-chunked item2/Wt2 layouts -----
__global__ __launch_bounds__(256) void fc_mfma2(
    const __half* __restrict__ A2, const __half* __restrict__ Wt2,
    const float* __restrict__ bias, __half* __restrict__ Y) {
    int lane = threadIdx.x & 63, wid = threadIdx.x >> 6;
    int job = blockIdx.x * 4 + wid;
    int mbase = job * 32;
    int cb = blockIdx.y * 128;
    int kg = lane >> 4, coll = lane & 15;
    f32x4 acc[2][8] = {};
    for (int s = 0; s < 16; ++s) {
        // wave's 64 lanes (coll x kg) cover contiguous 1KB blocks: coalesced
        f16x8 a0 = *(const f16x8*)(A2 + ((size_t)s * NBATCH + mbase + coll) * 32 + kg * 8);
        f16x8 a1 = *(const f16x8*)(A2 + ((size_t)s * NBATCH + mbase + 16 + coll) * 32 + kg * 8);
        #pragma unroll
        for (int f = 0; f < 8; ++f) {
            f16x8 b = *(const f16x8*)(Wt2 + ((size_t)s * HID + cb + f * 16 + coll) * 32 + kg * 8);
            acc[0][f] = __builtin_amdgcn_mfma_f32_16x16x32_f16(a0, b, acc[0][f], 0, 0, 0);
            acc[1][f] = __builtin_amdgcn_mfma_f32_16x16x32_f16(a1, b, acc[1][f], 0, 0, 0);
        }
    }
    #pragma unroll
    for (int f = 0; f < 8; ++f) {
        float bv = bias[cb + f * 16 + coll];
        #pragma unroll
        for (int r = 0; r < 2; ++r)
            #pragma unroll
            for (int g = 0; g < 4; ++g) {
                int m = mbase + r * 16 + kg * 4 + g;
                float v = acc[r][f][g] + bv;
                v = v > 0.f ? v : 0.f;
                Y[(size_t)m * HID + cb + f * 16 + coll] = __float2half(v);
            }
    }
}

// ------- conv_transpose: A + double-buffered B both in LDS, serial parity ----
template <int CIN, int COUT, int HIN, int R, int LOGH, int CF, int WAVES, int KSPLIT, int OH, int OB, int CHG>
__global__ __launch_bounds__(WAVES * 64) void convt_lds3(
    const __half* __restrict__ X, const __half* __restrict__ Bt,
    const float* __restrict__ bias, __half* __restrict__ Y) {
    constexpr int HH = HIN * HIN;
    constexpr int KTOT = 4 * CIN;
    constexpr int CINS = CIN / KSPLIT;
    constexpr int NSTEPS = CINS / 32;
    constexpr int SL = CIN / 8;
    constexpr int SLB = CINS / 8;
    constexpr int T = WAVES * 64;
    constexpr int PG = WAVES / CHG;
    constexpr int POS = PG * R * 16;
    constexpr int AROWS = POS;
    constexpr int AH = AROWS * CIN;
    constexpr int BROWS = CF * CHG * 16;
    constexpr int BH = BROWS * CINS;
    constexpr int SA = AROWS * SL;
    constexpr int SB = BROWS * SLB;
    constexpr int NSB = SB / T;
    constexpr int NST = 16 * KSPLIT;
    __shared__ _Float16 lds[AH + 2 * BH];

    int tid = threadIdx.x;
    int lane = tid & 63, w = tid >> 6;
    int kg = lane >> 4, coll = lane & 15;
    int pg = w / CHG, cg = w % CHG;
    int n0 = blockIdx.x * (POS >> (2 * LOGH));
    int cbb = blockIdx.y * (CF * CHG * 16);
    int cbase = cbb + cg * (CF * 16);
    int posbase = pg * (R * 16);

    const __half* Xs = X + (size_t)n0 * HH * CIN;
    #pragma unroll
    for (int q = 0; q < SA / T; ++q) {
        int i = tid + q * T;
        int row = i / SL, slot = i % SL;
        f16x8 v = *(const f16x8*)(Xs + (size_t)i * 8);
        *(f16x8*)(&lds[row * CIN + ((slot ^ (row & 7)) * 8)]) = v;
    }
    f16x8 breg[NSB];
    #pragma unroll
    for (int q = 0; q < NSB; ++q) {
        int i = tid + q * T;
        int o = i / SLB, sl = i % SLB;
        breg[q] = *(const f16x8*)(Bt + ((size_t)(cbb + o) * KTOT) + sl * 8);
    }
    #pragma unroll
    for (int q = 0; q < NSB; ++q) {
        int i = tid + q * T;
        int o = i / SLB, sl = i % SLB;
        *(f16x8*)(&lds[AH + o * CINS + ((sl ^ (o & 7)) * 8)]) = breg[q];
    }
    __syncthreads();

    int posl[R]; bool okr[R][3], okc[R][3];
    #pragma unroll
    for (int r = 0; r < R; ++r) {
        int p = posbase + r * 16 + coll;
        posl[r] = p;
        int rem = p & (HH - 1);
        int a = rem >> LOGH, b = rem & (HIN - 1);
        #pragma unroll
        for (int s = 0; s < 3; ++s) {
            okr[r][s] = (unsigned)(a + s - 1) < (unsigned)HIN;
            okc[r][s] = (unsigned)(b + s - 1) < (unsigned)HIN;
        }
    }

    float bvv[CF];
    #pragma unroll
    for (int f = 0; f < CF; ++f) bvv[f] = bias[cbase + f * 16 + coll];

    #pragma unroll
    for (int par = 0; par < 4; ++par) {
        const int pi = par & 1, pj = par >> 1;
        f32x4 acc[R][CF];
        #pragma unroll
        for (int r = 0; r < R; ++r)
            #pragma unroll
            for (int f = 0; f < CF; ++f)
                acc[r][f] = (f32x4){bvv[f], bvv[f], bvv[f], bvv[f]};

        #pragma unroll
        for (int tt = 0; tt < 4 * KSPLIT; ++tt) {
            const int s = par * 4 * KSPLIT + tt;
            const int tap = tt / KSPLIT;
            const int kh = tt % KSPLIT;
            const int buf = s & 1;
            if (s + 1 < NST) {
                const int s2 = s + 1;
                const int par2 = s2 / (4 * KSPLIT);
                const int tt2 = s2 % (4 * KSPLIT);
                const int tap2 = tt2 / KSPLIT;
                const int kh2 = tt2 % KSPLIT;
                #pragma unroll
                for (int q = 0; q < NSB; ++q) {
                    int i = tid + q * T;
                    int o = i / SLB, sl = i % SLB;
                    breg[q] = *(const f16x8*)(Bt +
                        ((size_t)(par2 * COUT + cbb + o) * KTOT +
                         tap2 * CIN + kh2 * CINS) + sl * 8);
                }
            }
            const int iu = (tap >> 1) + pi, iv = (tap & 1) + pj;
            const int delta = (iu - 1) * HIN + (iv - 1);
            int rp[R]; bool ok[R];
            #pragma unroll
            for (int r = 0; r < R; ++r) {
                int t = posl[r] + delta;
                rp[r] = min(max(t, 0), AROWS - 1);
                ok[r] = okr[r][iu] && okc[r][iv];
            }
            const _Float16* Bl = &lds[AH + buf * BH];
            #pragma unroll
            for (int cc = 0; cc < NSTEPS; ++cc) {
                const int slB = cc * 4 + kg;
                const int slA = kh * SLB + slB;
                f16x8 b[CF];
                #pragma unroll
                for (int f = 0; f < CF; ++f) {
                    int ob = cg * (CF * 16) + f * 16 + coll;
                    b[f] = *(const f16x8*)(&Bl[ob * CINS + ((slB ^ (ob & 7)) * 8)]);
                }
                f16x8 a[R];
                #pragma unroll
                for (int r = 0; r < R; ++r) {
                    f16x8 v = *(const f16x8*)(&lds[rp[r] * CIN +
                                                   ((slA ^ (rp[r] & 7)) * 8)]);
                    a[r] = ok[r] ? v : (f16x8){0, 0, 0, 0, 0, 0, 0, 0};
                }
                #pragma unroll
                for (int r = 0; r < R; ++r)
                    #pragma unroll
                    for (int f = 0; f < CF; ++f)
                        acc[r][f] = __builtin_amdgcn_mfma_f32_16x16x32_f16(
                            a[r], b[f], acc[r][f], 0, 0, 0);
            }
            if (s + 1 < NST) {
                #pragma unroll
                for (int q = 0; q < NSB; ++q) {
                    int i = tid + q * T;
                    int o = i / SLB, sl = i % SLB;
                    *(f16x8*)(&lds[AH + ((s + 1) & 1) * BH + o * CINS +
                                   ((sl ^ (o & 7)) * 8)]) = breg[q];
                }
                __syncthreads();
            }
        }

        #pragma unroll
        for (int r = 0; r < R; ++r) {
            #pragma unroll
            for (int g = 0; g < 4; ++g) {
                int p = posbase + r * 16 + kg * 4 + g;
                int ni = p >> (2 * LOGH);
                int rem = p & (HH - 1);
                int a2 = rem >> LOGH, b2 = rem & (HIN - 1);
                size_t ob = (((size_t)(n0 + ni) * OH + 2 * a2 + pi + OB) * OH +
                             2 * b2 + pj + OB) * COUT;
                #pragma unroll
                for (int f = 0; f < CF; ++f) {
                    float v = acc[r][f][g];
                    v = v > 0.f ? v : 0.f;
                    Y[ob + cbase + f * 16 + coll] = __float2half(v);
                }
            }
        }
    }
}

// ------- conv3+conv4 FUSED v7 (round-19, validated) ---------------------------
__global__ __launch_bounds__(512, 4) void conv34_fused7(
    const __half* __restrict__ X, const __half* __restrict__ Bt,
    const float* __restrict__ bias3, const __half* __restrict__ W4m,
    const float* __restrict__ bias4, float* __restrict__ out) {
    constexpr int CIN = 64, HIN = 16, HH = 256, KTOT = 256;
    constexpr int SL = 8, T = 512, AROWS = 256, AH = AROWS * CIN;
    constexpr int BH = 32 * KTOT;
    constexpr int PS = 1164;
    __shared__ _Float16 lds[AH + BH];       // 49,152 B

    int tid = threadIdx.x;
    int lane = tid & 63, w = tid >> 6;
    int kg = lane >> 4, coll = lane & 15;
    int n = blockIdx.x;
    int posbase = w * 32;

    const __half* Xs = X + (size_t)n * HH * CIN;
    #pragma unroll
    for (int q = 0; q < 4; ++q) {
        int i = tid + q * T;
        int row = i / SL, slot = i % SL;
        f16x8 v = *(const f16x8*)(Xs + (size_t)i * 8);
        *(f16x8*)(&lds[row * CIN + ((slot ^ (row & 7)) * 8)]) = v;
    }
    #pragma unroll
    for (int q = 0; q < 2; ++q) {
        int i = tid + q * T;
        int o = i >> 5, sl = i & 31;
        f16x8 b0 = *(const f16x8*)(Bt + (size_t)o * KTOT + sl * 8);
        *(f16x8*)(&lds[AH + o * KTOT + ((sl ^ (o & 7)) * 8)]) = b0;
    }
    __syncthreads();

    int posl[2]; bool okr[2][3], okc[2][3];
    #pragma unroll
    for (int r = 0; r < 2; ++r) {
        int p = posbase + r * 16 + coll;
        posl[r] = p;
        int a = p >> 4, b = p & 15;
        #pragma unroll
        for (int s = 0; s < 3; ++s) {
            okr[r][s] = (unsigned)(a + s - 1) < (unsigned)HIN;
            okc[r][s] = (unsigned)(b + s - 1) < (unsigned)HIN;
        }
    }

    f32x4 ib[2];
    #pragma unroll
    for (int f = 0; f < 2; ++f)
        #pragma unroll
        for (int g = 0; g < 4; ++g) ib[f][g] = bias3[f * 16 + kg * 4 + g];

    f32x4 acc[4][2][2];
    #pragma unroll
    for (int par = 0; par < 4; ++par)
        #pragma unroll
        for (int r = 0; r < 2; ++r) {
            acc[par][r][0] = ib[0];
            acc[par][r][1] = ib[1];
        }

    f16x8 breg[2];
    #pragma unroll
    for (int par = 0; par < 4; ++par) {
        const int pi = par & 1, pj = par >> 1;
        if (par < 3) {
            #pragma unroll
            for (int q = 0; q < 2; ++q) {
                int i = tid + q * T;
                int o = i >> 5, sl = i & 31;
                breg[q] = *(const f16x8*)(Bt + ((size_t)((par + 1) * 32 + o) * KTOT) + sl * 8);
            }
        }
        const _Float16* Bl = &lds[AH];
        #pragma unroll
        for (int tap = 0; tap < 4; ++tap) {
            const int iu = (tap >> 1) + pi, iv = (tap & 1) + pj;
            const int delta = (iu - 1) * HIN + (iv - 1);
            int rp[2]; bool ok[2];
            #pragma unroll
            for (int r = 0; r < 2; ++r) {
                int t2 = posl[r] + delta;
                rp[r] = min(max(t2, 0), AROWS - 1);
                ok[r] = okr[r][iu] && okc[r][iv];
            }
            #pragma unroll
            for (int cc = 0; cc < 2; ++cc) {
                const int slA = cc * 4 + kg;
                const int slB = tap * 8 + slA;
                f16x8 b[2];
                #pragma unroll
                for (int f = 0; f < 2; ++f)
                    b[f] = *(const f16x8*)(&Bl[(f * 16 + coll) * KTOT +
                                               ((slB ^ (coll & 7)) * 8)]);
                f16x8 a[2];
                #pragma unroll
                for (int r = 0; r < 2; ++r) {
                    f16x8 v = *(const f16x8*)(&lds[rp[r] * CIN +
                                                   ((slA ^ (rp[r] & 7)) * 8)]);
                    a[r] = ok[r] ? v : (f16x8){0, 0, 0, 0, 0, 0, 0, 0};
                }
                #pragma unroll
                for (int r = 0; r < 2; ++r)
                    #pragma unroll
                    for (int f = 0; f < 2; ++f)
                        acc[par][r][f] = __builtin_amdgcn_mfma_f32_16x16x32_f16(
                            b[f], a[r], acc[par][r][f], 0, 0, 0);
            }
        }
        if (par < 3) {
            __syncthreads();
            #pragma unroll
            for (int q = 0; q < 2; ++q) {
                int i = tid + q * T;
                int o = i >> 5, sl = i & 31;
                *(f16x8*)(&lds[AH + o * KTOT + ((sl ^ (o & 7)) * 8)]) = breg[q];
            }
            __syncthreads();
        }
    }
    __syncthreads();

    int a_base = w * 4;
    int lane_base = a_base * 34 + coll;
    float bv4 = bias4[0];
    f32x4 acc4[8];
    #pragma unroll
    for (int g2 = 0; g2 < 8; ++g2) acc4[g2] = (f32x4){bv4, bv4, bv4, bv4};

    #pragma unroll
    for (int f = 0; f < 2; ++f) {
        if (f == 0) {
            for (int i = tid; i < 264; i += T) {
                int posi = i >> 1, q = i & 1;
                int rr, sc;
                if (posi < 68) { rr = (posi < 34) ? 0 : 33; sc = posi % 34; }
                else { int e = posi - 68; rr = 1 + (e >> 1); sc = (e & 1) ? 33 : 0; }
                int site = rr * 34 + sc;
                int ss = site ^ ((site >> 2) & 7);
                *(f16x8*)(&lds[(q * PS + ss) * 8]) = (f16x8){0, 0, 0, 0, 0, 0, 0, 0};
            }
        }
        #pragma unroll
        for (int par = 0; par < 4; ++par) {
            const int pi = par & 1, pj = par >> 1;
            #pragma unroll
            for (int r = 0; r < 2; ++r) {
                int p = posl[r];
                int a2 = p >> 4, b2 = p & 15;
                int site = (2 * a2 + pi + 1) * 34 + (2 * b2 + pj + 1);
                int ss = site ^ ((site >> 2) & 7);
                f16x4 pv;
                #pragma unroll
                for (int g = 0; g < 4; ++g) {
                    float v = acc[par][r][f][g];
                    v = v > 0.f ? v : 0.f;
                    pv[g] = (_Float16)v;
                }
                *(f16x4*)(&lds[((kg >> 1) * PS + ss) * 8 + (kg & 1) * 4]) = pv;
            }
        }
        __syncthreads();
        #pragma unroll
        for (int sp = 0; sp < 5; ++sp) {
            f16x8 aw = *(const f16x8*)(W4m + ((size_t)(f * 5 + sp) * 16 + coll) * 32 + kg * 8);
            int s01 = sp * 2 + (kg >> 1);
            int bs = (s01 >= 9) ? 0 : (s01 / 3) * 34 + (s01 % 3);
            int lb = lane_base + bs;
            #pragma unroll
            for (int g2 = 0; g2 < 8; ++g2) {
                int a_loc = g2 >> 1, bh = g2 & 1;
                int site = lb + a_loc * 34 + bh * 16;
                int ss = site ^ ((site >> 2) & 7);
                f16x8 bx = *(const f16x8*)(&lds[((kg & 1) * PS + ss) * 8]);
                acc4[g2] = __builtin_amdgcn_mfma_f32_16x16x32_f16(aw, bx, acc4[g2], 0, 0, 0);
            }
        }
        if (f == 0) __syncthreads();
    }
    if (kg == 0) {
        #pragma unroll
        for (int g2 = 0; g2 < 8; ++g2) {
            int a = a_base + (g2 >> 1);
            int bcol = (g2 & 1) * 32 + 2 * coll;
            float2 v0 = {acc4[g2][0], acc4[g2][2]};
            float2 v1 = {acc4[g2][1], acc4[g2][3]};
            *(float2*)(&out[((size_t)n * 64 + 2 * a) * 64 + bcol]) = v0;
            *(float2*)(&out[((size_t)n * 64 + 2 * a + 1) * 64 + bcol]) = v1;
        }
    }
}

// ---------------- launch -----------------------------------------------------
extern "C" void kernel_launch(void* const* d_in, const int* in_sizes, int n_in,
                              void* d_out, int out_size, void* d_ws, size_t ws_size,
                              hipStream_t stream) {
    const float* angles   = (const float*)d_in[0];
    const float* item_rep = (const float*)d_in[1];
    const float* W        = (const float*)d_in[2];
    const float* bfc      = (const float*)d_in[3];
    const float* k1       = (const float*)d_in[4];
    const float* b1       = (const float*)d_in[5];
    const float* k2       = (const float*)d_in[6];
    const float* b2       = (const float*)d_in[7];
    const float* k3       = (const float*)d_in[8];
    const float* b3       = (const float*)d_in[9];
    const float* k4       = (const float*)d_in[10];
    const float* b4       = (const float*)d_in[11];

    char* ws = (char*)d_ws;
    float*  Ctab  = (float*)(ws + 0);                 //  32 KB
    __half* item2 = (__half*)(ws + 32768);            //   2 MB (k-chunked)
    __half* Bt1   = (__half*)(ws + 2129920);          //   1 MB
    __half* Bt2   = (__half*)(ws + 3178496);          // 256 KB
    __half* Bt3   = (__half*)(ws + 3440640);          //  64 KB
    __half* W4m   = (__half*)(ws + 3506176);          //  10 KB
    __half* x0    = (__half*)(ws + 4194304);          //  16 MB -> 20,971,520
    __half* x1    = (__half*)(ws + 20971520);         //  32 MB -> 54,525,952
    __half* Wt2   = (__half*)(ws + 121634816);        //   4 MB (k-chunked, dead region)
    __half* x2    = (__half*)(ws + 155713536);        //  64 MB -> 222,822,400
    float*  out   = (float*)d_out;

    // ONE fused prep launch: coef + fcw(k-chunked) + convw x3 + w4m
    prep_all<<<582, 256, 0, stream>>>(W, k1, k2, k3, k4,
                                      Ctab, Wt2, Bt1, Bt2, Bt3, W4m);
    // wigner v2 (k-chunked output)
    wigner_kernel2<<<NBATCH, 64, 0, stream>>>(angles, item_rep, Ctab, item2);
    // FC with fully coalesced operand loads
    fc_mfma2<<<dim3(16, 32), 256, 0, stream>>>(item2, Wt2, bfc, x0);
    // conv1: 4x4x256 -> 8x8x128  (4 waves = 2 pg x 2 cg, R=2, KSPLIT=4)
    convt_lds3<256, 128, 4, 2, 2, 4, 4, 4, 8, 0, 2><<<dim3(512, 1), 256, 0, stream>>>(x0, Bt1, b1, x1);
    // conv2: 8x8x128 -> 16x16x64 (4 waves, R=2, CF=4, CHG=1)
    convt_lds3<128, 64, 8, 2, 3, 4, 4, 1, 16, 0, 1><<<dim3(1024, 1), 256, 0, stream>>>(x1, Bt2, b2, x2);
    // conv3+conv4 fused v7
    conv34_fused7<<<NBATCH, 512, 0, stream>>>(x2, Bt3, b3, W4m, b4, out);
}